// Round 1
// baseline (1082.463 us; speedup 1.0000x reference)
//
#include <hip/hip_runtime.h>
#include <math.h>

// Problem constants
#define NCH 72            // total channels (8*1 + 8*3 + 8*5)
#define SP  32768         // 32^3 spatial
#define NBATCH 8
#define NTOT (NBATCH*SP)  // per-channel element count = 262144

// ws layout (float offsets)
#define WS_SUMX   0       // 72
#define WS_SUMSQ  72      // 72
#define WS_SCALE  144     // 72 (per input channel inverse-std)
#define WS_BIAS   216     // 72
#define WS_K      288     // 72*72*27 = 139968 floats

__device__ __forceinline__ void chmap(int c, int& f, int& m, int& d, int& dim) {
  if (c < 8)       { f = 0; m = c;          d = 0;          dim = 1; }
  else if (c < 32) { f = 1; m = (c - 8)/3;  d = (c - 8)%3;  dim = 3; }
  else             { f = 2; m = (c - 32)/5; d = (c - 32)%5; dim = 5; }
}

// ---------------- stats: per-channel sum(x), sum(x^2) ----------------
__global__ __launch_bounds__(256) void stats_kernel(const float* __restrict__ x,
                                                    float* __restrict__ ws) {
  const int c = blockIdx.x;   // channel 0..71
  const int b = blockIdx.y;   // batch 0..7
  const float4* p = (const float4*)(x + ((size_t)b * NCH + c) * SP);
  float sx = 0.f, sq = 0.f;
  for (int i = threadIdx.x; i < SP/4; i += 256) {
    float4 v = p[i];
    sx += v.x + v.y + v.z + v.w;
    sq += v.x*v.x + v.y*v.y + v.z*v.z + v.w*v.w;
  }
  #pragma unroll
  for (int o = 32; o > 0; o >>= 1) {
    sx += __shfl_down(sx, o, 64);
    sq += __shfl_down(sq, o, 64);
  }
  __shared__ float ssx[4], ssq[4];
  const int wid = threadIdx.x >> 6;
  if ((threadIdx.x & 63) == 0) { ssx[wid] = sx; ssq[wid] = sq; }
  __syncthreads();
  if (threadIdx.x == 0) {
    float tsx = ssx[0] + ssx[1] + ssx[2] + ssx[3];
    float tsq = ssq[0] + ssq[1] + ssq[2] + ssq[3];
    atomicAdd(&ws[WS_SUMX  + c], tsx);
    atomicAdd(&ws[WS_SUMSQ + c], tsq);
  }
}

// ---------------- finalize: scales, means -> bias ----------------
__global__ __launch_bounds__(128) void finalize_kernel(const float* __restrict__ weight,
                                                       const float* __restrict__ basis00,
                                                       float* __restrict__ ws) {
  __shared__ float s_mean[8], s_scale[8];
  const int c = threadIdx.x;
  const float invN = 1.0f / (float)NTOT;
  if (c < NCH) {
    float norm;
    if (c < 8) {
      float m = ws[WS_SUMX + c] * invN;
      norm = ws[WS_SUMSQ + c] * invN - m * m;   // E[(x-mu)^2]
      s_mean[c] = m;
    } else if (c < 32) {
      int m0 = 8 + ((c - 8) / 3) * 3;
      norm = (ws[WS_SUMSQ+m0] + ws[WS_SUMSQ+m0+1] + ws[WS_SUMSQ+m0+2]) * invN;
    } else {
      int m0 = 32 + ((c - 32) / 5) * 5;
      norm = (ws[WS_SUMSQ+m0] + ws[WS_SUMSQ+m0+1] + ws[WS_SUMSQ+m0+2]
            + ws[WS_SUMSQ+m0+3] + ws[WS_SUMSQ+m0+4]) * invN;
    }
    float sc = 1.0f / sqrtf(norm + 1e-5f);
    ws[WS_SCALE + c] = sc;
    if (c < 8) s_scale[c] = sc;
  }
  __syncthreads();
  if (c < NCH) {
    float bia = 0.f;
    if (c < 8) {
      float id0 = 0.f, id1 = 0.f;
      #pragma unroll
      for (int t = 0; t < 27; ++t) { id0 += basis00[t]; id1 += basis00[27 + t]; }
      #pragma unroll
      for (int v = 0; v < 8; ++v) {
        float s  = s_scale[v];
        float w0 = weight[(c*8 + v)*2 + 0] * s;
        float w1 = weight[(c*8 + v)*2 + 1] * s;
        bia -= (w0 * id0 + w1 * id1) * s_mean[v];
      }
    }
    ws[WS_BIAS + c] = bia;
  }
}

// ---------------- build dynamic conv kernel K[72][72][27] ----------------
__global__ __launch_bounds__(128) void build_kernel(const float* __restrict__ weight,
    float* __restrict__ ws,
    const float* __restrict__ b00, const float* __restrict__ b01, const float* __restrict__ b02,
    const float* __restrict__ b10, const float* __restrict__ b11, const float* __restrict__ b12,
    const float* __restrict__ b20, const float* __restrict__ b21, const float* __restrict__ b22) {
  const int tid = blockIdx.x * blockDim.x + threadIdx.x;
  if (tid >= NCH * NCH) return;
  const int co = tid / NCH, ci = tid % NCH;
  int fi, u, dd, di; chmap(co, fi, u, dd, di);
  int fj, v, ee, dj; chmap(ci, fj, v, ee, dj);
  const float* bs[9] = {b00, b01, b02, b10, b11, b12, b20, b21, b22};
  const float* basis = bs[fi * 3 + fj];
  const float sc = ws[WS_SCALE + ci];
  const float* wp = weight + (fi * 3 + fj) * 128 + (u * 8 + v) * 2;
  const float w0 = wp[0] * sc, w1 = wp[1] * sc;
  const float* p0 = basis + (dd * dj + ee) * 27;        // b_el = 0
  const float* p1 = basis + ((di + dd) * dj + ee) * 27; // b_el = 1
  float* o = ws + WS_K + (co * NCH + ci) * 27;
  #pragma unroll
  for (int t = 0; t < 27; ++t) o[t] = w0 * p0[t] + w1 * p1[t];
}

// ---------------- conv3d VALID + bias ----------------
// block: 256 threads; tx=tid&15 -> out cols {2tx, 2tx+1}; ty=tid>>4 -> out rows {ty, ty+16}
// grid: (9 co-groups, 30 z, 8 batch); each block does full 30x30 (y,x) plane, 8 out channels
__global__ __launch_bounds__(256) void conv_kernel(const float* __restrict__ x,
                                                   const float* __restrict__ ws,
                                                   float* __restrict__ out) {
  __shared__ float sx[1032];          // one 32x32 input plane (+pad for edge-lane b64 reads)
  const int tid = threadIdx.x;
  const int tx  = tid & 15;
  const int ty  = tid >> 4;
  const int co0 = blockIdx.x * 8;
  const int z   = blockIdx.y;
  const int b   = blockIdx.z;
  const float* __restrict__ K    = ws + WS_K;
  const float* __restrict__ bias = ws + WS_BIAS;

  float acc[8][4];
  #pragma unroll
  for (int i = 0; i < 8; ++i)
    #pragma unroll
    for (int j = 0; j < 4; ++j) acc[i][j] = 0.f;

  const float* xb = x + (size_t)b * NCH * SP;
  for (int ci = 0; ci < NCH; ++ci) {
    const float* xc = xb + (size_t)ci * SP + z * 1024;  // plane z (+dz*1024 below)
    #pragma unroll
    for (int dz = 0; dz < 3; ++dz) {
      __syncthreads();   // protect previous stage's LDS reads
      ((float4*)sx)[tid] = ((const float4*)(xc + dz * 1024))[tid];
      __syncthreads();

      // register-cache the 6 rows x 4 cols window this thread needs
      float xr[6][4];
      #pragma unroll
      for (int dy = 0; dy < 3; ++dy) {
        const int ra = ty + dy;                 // <= 17
        const int rb = (ty + 16 + dy) & 31;     // clamp; masked lanes produce garbage (unused)
        const float* pa = &sx[ra * 32 + 2 * tx];
        const float* pb = &sx[rb * 32 + 2 * tx];
        xr[dy][0]   = pa[0]; xr[dy][1]   = pa[1]; xr[dy][2]   = pa[2]; xr[dy][3]   = pa[3];
        xr[dy+3][0] = pb[0]; xr[dy+3][1] = pb[1]; xr[dy+3][2] = pb[2]; xr[dy+3][3] = pb[3];
      }

      const float* kbase = K + (co0 * NCH + ci) * 27 + dz * 9;  // block-uniform -> s_load
      #pragma unroll
      for (int co = 0; co < 8; ++co) {
        const float* kp = kbase + co * (NCH * 27);
        float kk[9];
        #pragma unroll
        for (int t = 0; t < 9; ++t) kk[t] = kp[t];
        #pragma unroll
        for (int dy = 0; dy < 3; ++dy) {
          #pragma unroll
          for (int dx = 0; dx < 3; ++dx) {
            const float k = kk[dy * 3 + dx];
            acc[co][0] = fmaf(k, xr[dy][dx],     acc[co][0]);
            acc[co][1] = fmaf(k, xr[dy][dx + 1], acc[co][1]);
            acc[co][2] = fmaf(k, xr[dy+3][dx],     acc[co][2]);
            acc[co][3] = fmaf(k, xr[dy+3][dx + 1], acc[co][3]);
          }
        }
      }
    }
  }

  // epilogue: bias + masked float2 stores
  if (tx < 15) {   // cols 2tx, 2tx+1 both < 30
    const int c0 = 2 * tx;
    #pragma unroll
    for (int co = 0; co < 8; ++co) {
      const float bv = bias[co0 + co];
      const int obase = ((b * NCH + co0 + co) * 30 + z) * 900;
      float2 r0; r0.x = acc[co][0] + bv; r0.y = acc[co][1] + bv;
      *(float2*)&out[obase + ty * 30 + c0] = r0;
      if (ty < 14) {  // row ty+16 < 30
        float2 r1; r1.x = acc[co][2] + bv; r1.y = acc[co][3] + bv;
        *(float2*)&out[obase + (ty + 16) * 30 + c0] = r1;
      }
    }
  }
}

extern "C" void kernel_launch(void* const* d_in, const int* in_sizes, int n_in,
                              void* d_out, int out_size, void* d_ws, size_t ws_size,
                              hipStream_t stream) {
  const float* x = (const float*)d_in[0];
  const float* w = (const float*)d_in[1];
  const float* bs[9];
  for (int i = 0; i < 9; ++i) bs[i] = (const float*)d_in[2 + i];
  float* ws  = (float*)d_ws;
  float* out = (float*)d_out;

  // zero the accumulator region (harness poisons ws with 0xAA every call)
  hipMemsetAsync(d_ws, 0, 144 * sizeof(float), stream);

  stats_kernel<<<dim3(NCH, NBATCH), 256, 0, stream>>>(x, ws);
  finalize_kernel<<<1, 128, 0, stream>>>(w, bs[0], ws);
  build_kernel<<<(NCH * NCH + 127) / 128, 128, 0, stream>>>(
      w, ws, bs[0], bs[1], bs[2], bs[3], bs[4], bs[5], bs[6], bs[7], bs[8]);
  conv_kernel<<<dim3(9, 30, NBATCH), 256, 0, stream>>>(x, ws, out);
}

// Round 2
// 439.691 us; speedup vs baseline: 2.4619x; 2.4619x over previous
//
#include <hip/hip_runtime.h>
#include <hip/hip_fp16.h>
#include <math.h>

// Problem constants
#define NCH 72            // total channels (8*1 + 8*3 + 8*5)
#define SP  32768         // 32^3 spatial
#define NBATCH 8
#define NTOT (NBATCH*SP)  // per-channel element count = 262144

// ws layout (float offsets)
#define WS_SUMX   0       // 72
#define WS_SUMSQ  72      // 72
#define WS_SCALE  144     // 72 (per input channel inverse-std)
#define WS_BIAS   216     // 72
#define WS_K      288     // fp16 kernel matrix: 80co * 9tap * 224kk shorts = 322,560 B

#define KCO_STRIDE 2016   // 9*224 elements per co row
#define KTAP_STRIDE 224
#define CP 88             // ci slots (72 real + 16 zero; 176B x-stride -> conflict-free b128)
#define XW 34             // x slots (32 real + 2 clamp)
#define XROW (XW*CP)      // 2992 shorts per (y) row
#define XSLOT (6*XROW)    // 17952 shorts per z-plane slot

typedef __attribute__((ext_vector_type(8))) _Float16 half8;
typedef __attribute__((ext_vector_type(4))) float float4v;

__device__ __forceinline__ void chmap(int c, int& f, int& m, int& d, int& dim) {
  if (c < 8)       { f = 0; m = c;          d = 0;          dim = 1; }
  else if (c < 32) { f = 1; m = (c - 8)/3;  d = (c - 8)%3;  dim = 3; }
  else             { f = 2; m = (c - 32)/5; d = (c - 32)%5; dim = 5; }
}

// ---------------- stats: per-channel sum(x), sum(x^2) ----------------
__global__ __launch_bounds__(256) void stats_kernel(const float* __restrict__ x,
                                                    float* __restrict__ ws) {
  const int c = blockIdx.x;   // channel 0..71
  const int b = blockIdx.y;   // batch 0..7
  const float4* p = (const float4*)(x + ((size_t)b * NCH + c) * SP);
  float sx = 0.f, sq = 0.f;
  for (int i = threadIdx.x; i < SP/4; i += 256) {
    float4 v = p[i];
    sx += v.x + v.y + v.z + v.w;
    sq += v.x*v.x + v.y*v.y + v.z*v.z + v.w*v.w;
  }
  #pragma unroll
  for (int o = 32; o > 0; o >>= 1) {
    sx += __shfl_down(sx, o, 64);
    sq += __shfl_down(sq, o, 64);
  }
  __shared__ float ssx[4], ssq[4];
  const int wid = threadIdx.x >> 6;
  if ((threadIdx.x & 63) == 0) { ssx[wid] = sx; ssq[wid] = sq; }
  __syncthreads();
  if (threadIdx.x == 0) {
    float tsx = ssx[0] + ssx[1] + ssx[2] + ssx[3];
    float tsq = ssq[0] + ssq[1] + ssq[2] + ssq[3];
    atomicAdd(&ws[WS_SUMX  + c], tsx);
    atomicAdd(&ws[WS_SUMSQ + c], tsq);
  }
}

// ---------------- finalize: scales, means -> bias ----------------
__global__ __launch_bounds__(128) void finalize_kernel(const float* __restrict__ weight,
                                                       const float* __restrict__ basis00,
                                                       float* __restrict__ ws) {
  __shared__ float s_mean[8], s_scale[8];
  const int c = threadIdx.x;
  const float invN = 1.0f / (float)NTOT;
  if (c < NCH) {
    float norm;
    if (c < 8) {
      float m = ws[WS_SUMX + c] * invN;
      norm = ws[WS_SUMSQ + c] * invN - m * m;   // E[(x-mu)^2]
      s_mean[c] = m;
    } else if (c < 32) {
      int m0 = 8 + ((c - 8) / 3) * 3;
      norm = (ws[WS_SUMSQ+m0] + ws[WS_SUMSQ+m0+1] + ws[WS_SUMSQ+m0+2]) * invN;
    } else {
      int m0 = 32 + ((c - 32) / 5) * 5;
      norm = (ws[WS_SUMSQ+m0] + ws[WS_SUMSQ+m0+1] + ws[WS_SUMSQ+m0+2]
            + ws[WS_SUMSQ+m0+3] + ws[WS_SUMSQ+m0+4]) * invN;
    }
    float sc = 1.0f / sqrtf(norm + 1e-5f);
    ws[WS_SCALE + c] = sc;
    if (c < 8) s_scale[c] = sc;
  }
  __syncthreads();
  if (c < NCH) {
    float bia = 0.f;
    if (c < 8) {
      float id0 = 0.f, id1 = 0.f;
      #pragma unroll
      for (int t = 0; t < 27; ++t) { id0 += basis00[t]; id1 += basis00[27 + t]; }
      #pragma unroll
      for (int v = 0; v < 8; ++v) {
        float s  = s_scale[v];
        float w0 = weight[(c*8 + v)*2 + 0] * s;
        float w1 = weight[(c*8 + v)*2 + 1] * s;
        bia -= (w0 * id0 + w1 * id1) * s_mean[v];
      }
    }
    ws[WS_BIAS + c] = bia;
  }
}

// ---------------- build fp16 kernel matrix Kmat[co(80)][tap(9)][kk(224)] ----------------
// kk = dx*72 + ci for kk<216; kk>=216 and co>=72 are zero pads.
__global__ __launch_bounds__(256) void build_half_kernel(const float* __restrict__ weight,
    float* __restrict__ ws,
    const float* __restrict__ b00, const float* __restrict__ b01, const float* __restrict__ b02,
    const float* __restrict__ b10, const float* __restrict__ b11, const float* __restrict__ b12,
    const float* __restrict__ b20, const float* __restrict__ b21, const float* __restrict__ b22) {
  const int tid = blockIdx.x * 256 + threadIdx.x;
  if (tid >= 80 * KCO_STRIDE) return;
  const int co  = tid / KCO_STRIDE;
  const int rem = tid - co * KCO_STRIDE;
  const int tap = rem / KTAP_STRIDE;   // dz*3+dy
  const int kk  = rem - tap * KTAP_STRIDE;
  short val = 0;
  if (co < NCH && kk < 216) {
    const int dx = kk / 72, ci = kk - dx * 72;
    int fi, u, dd, di; chmap(co, fi, u, dd, di);
    int fj, v, ee, dj; chmap(ci, fj, v, ee, dj);
    const float* bs[9] = {b00, b01, b02, b10, b11, b12, b20, b21, b22};
    const float* basis = bs[fi * 3 + fj];
    const float sc = ws[WS_SCALE + ci];
    const float* wp = weight + (fi * 3 + fj) * 128 + (u * 8 + v) * 2;
    const float w0 = wp[0] * sc, w1 = wp[1] * sc;
    const int t = tap * 3 + dx;
    const float f = w0 * basis[(dd * dj + ee) * 27 + t]
                  + w1 * basis[((di + dd) * dj + ee) * 27 + t];
    __half h = __float2half(f);
    val = __half_as_short(h);
  }
  ((short*)(ws + WS_K))[tid] = val;   // layout co*2016 + tap*224 + kk == tid
}

// ---------------- staging: one z-plane -> LDS slot (transpose to [y][x][ci], fp16) ----------------
__device__ __forceinline__ void stage_plane(const float* __restrict__ xb, int zp, int yr0,
                                            short* sX) {
  short* dst = sX + (zp & 3) * XSLOT;
  for (int i = threadIdx.x; i < NCH * 204; i += 256) {   // 204 = 6*34 positions
    const int ci  = i / 204;
    const int rem = i - ci * 204;
    const int yp  = rem / XW;
    const int xx  = rem - yp * XW;
    int ys = yr0 + yp; if (ys > 31) ys = 31;   // clamp: affects only discarded outputs
    int xs = xx;       if (xs > 31) xs = 31;
    const float v = xb[(size_t)ci * SP + zp * 1024 + ys * 32 + xs];
    __half h = __float2half(v);
    dst[rem * CP + ci] = __half_as_short(h);
  }
}

// ---------------- MFMA implicit-GEMM conv ----------------
// grid (yt=8, zc=4, b=8) = 256 blocks; block = 4 waves; wave w = output row y0+w.
// Per 2-z iteration: wave computes 4 m-subtiles (2z x 2x-halves) x 5 co-tiles.
__global__ __launch_bounds__(256) void conv_mfma(const float* __restrict__ x,
                                                 const float* __restrict__ ws,
                                                 float* __restrict__ out) {
  __shared__ __align__(16) short sX[4 * XSLOT];   // 143,616 B
  const int tid  = threadIdx.x;
  const int lane = tid & 63;
  const int w    = tid >> 6;        // wave id = output-row offset
  const int lx   = lane & 15;
  const int q    = lane >> 4;
  const int yt = blockIdx.x, zc = blockIdx.y, b = blockIdx.z;
  const int y0 = yt * 4, y = y0 + w;
  const int z0 = zc * 8, z1 = (z0 + 8 < 30) ? z0 + 8 : 30;
  const float* __restrict__ xb   = x + (size_t)b * NCH * SP;
  const short* __restrict__ Kmat = (const short*)(ws + WS_K);
  const float* __restrict__ bias = ws + WS_BIAS;

  // per-kc A-fragment k-offsets: kk0 = kc*32 + q*8 -> (dx, ci0); 8-runs never cross dx blocks
  int dxk[7], cik[7];
  #pragma unroll
  for (int kc = 0; kc < 7; ++kc) {
    const int kk0 = kc * 32 + q * 8;
    const int dx = (kk0 >= 144) ? 2 : ((kk0 >= 72) ? 1 : 0);   // kk0=216 -> ci0=72 (zero pad)
    dxk[kc] = dx;
    cik[kc] = kk0 - dx * 72;
  }
  const short* bbase = Kmat + lx * KCO_STRIDE + q * 8;

  // zero the ci pad region (72..87) of all 4 slots once; never dirtied afterwards
  for (int i = tid; i < 4 * 204 * 16; i += 256) {
    const int sl  = i / (204 * 16);
    const int r2  = i - sl * (204 * 16);
    const int pos = r2 >> 4;
    sX[sl * XSLOT + pos * CP + 72 + (r2 & 15)] = 0;
  }

  // prime the 4-plane rolling window
  stage_plane(xb, z0,     y0, sX);
  stage_plane(xb, z0 + 1, y0, sX);
  stage_plane(xb, z0 + 2, y0, sX);
  stage_plane(xb, z0 + 3, y0, sX);

  for (int zb = z0; zb < z1; zb += 2) {
    if (zb > z0) {
      __syncthreads();                       // drain previous iteration's LDS reads
      stage_plane(xb, zb + 2, y0, sX);       // zb+3 <= 31 always
      stage_plane(xb, zb + 3, y0, sX);
    }
    __syncthreads();

    float4v acc[2][2][5];
    #pragma unroll
    for (int sz = 0; sz < 2; ++sz)
      #pragma unroll
      for (int s = 0; s < 2; ++s)
        #pragma unroll
        for (int cj = 0; cj < 5; ++cj)
          acc[sz][s][cj] = (float4v){0.f, 0.f, 0.f, 0.f};

    for (int tap = 0; tap < 9; ++tap) {
      const int dz = tap / 3, dy = tap - dz * 3;
      const short* ab0 = sX + ((zb + dz) & 3)     * XSLOT + (w + dy) * XROW;
      const short* ab1 = sX + ((zb + 1 + dz) & 3) * XSLOT + (w + dy) * XROW;
      #pragma unroll
      for (int kc = 0; kc < 7; ++kc) {
        const short* bp = bbase + tap * KTAP_STRIDE + kc * 32;
        half8 bf[5];
        #pragma unroll
        for (int cj = 0; cj < 5; ++cj)
          bf[cj] = *(const half8*)(bp + cj * 16 * KCO_STRIDE);
        const int xoff = (lx + dxk[kc]) * CP + cik[kc];
        const half8 a00 = *(const half8*)(ab0 + xoff);
        const half8 a01 = *(const half8*)(ab0 + 16 * CP + xoff);
        const half8 a10 = *(const half8*)(ab1 + xoff);
        const half8 a11 = *(const half8*)(ab1 + 16 * CP + xoff);
        #pragma unroll
        for (int cj = 0; cj < 5; ++cj) {
          acc[0][0][cj] = __builtin_amdgcn_mfma_f32_16x16x32_f16(a00, bf[cj], acc[0][0][cj], 0, 0, 0);
          acc[0][1][cj] = __builtin_amdgcn_mfma_f32_16x16x32_f16(a01, bf[cj], acc[0][1][cj], 0, 0, 0);
          acc[1][0][cj] = __builtin_amdgcn_mfma_f32_16x16x32_f16(a10, bf[cj], acc[1][0][cj], 0, 0, 0);
          acc[1][1][cj] = __builtin_amdgcn_mfma_f32_16x16x32_f16(a11, bf[cj], acc[1][1][cj], 0, 0, 0);
        }
      }
    }

    // epilogue: D layout col(co)=lane&15, row(m=x)=q*4+reg
    if (y < 30) {
      #pragma unroll
      for (int cj = 0; cj < 5; ++cj) {
        const int co = cj * 16 + lx;
        if (co < NCH) {
          const float bv = bias[co];
          #pragma unroll
          for (int sz = 0; sz < 2; ++sz) {
            const int zo = zb + sz;
            float* ob = out + ((size_t)(b * NCH + co) * 30 + zo) * 900 + y * 30;
            #pragma unroll
            for (int s = 0; s < 2; ++s) {
              const int x0 = s * 16 + q * 4;
              const float4v v = acc[sz][s][cj];
              float2 p0; p0.x = v[0] + bv; p0.y = v[1] + bv;
              *(float2*)(ob + x0) = p0;                       // x0 <= 28 always valid pair
              if (x0 + 2 < 30) {
                float2 p1; p1.x = v[2] + bv; p1.y = v[3] + bv;
                *(float2*)(ob + x0 + 2) = p1;
              }
            }
          }
        }
      }
    }
  }
}

extern "C" void kernel_launch(void* const* d_in, const int* in_sizes, int n_in,
                              void* d_out, int out_size, void* d_ws, size_t ws_size,
                              hipStream_t stream) {
  const float* x = (const float*)d_in[0];
  const float* w = (const float*)d_in[1];
  const float* bs[9];
  for (int i = 0; i < 9; ++i) bs[i] = (const float*)d_in[2 + i];
  float* ws  = (float*)d_ws;
  float* out = (float*)d_out;

  // zero the stats accumulators (ws is poisoned 0xAA before every call)
  hipMemsetAsync(d_ws, 0, 144 * sizeof(float), stream);

  stats_kernel<<<dim3(NCH, NBATCH), 256, 0, stream>>>(x, ws);
  finalize_kernel<<<1, 128, 0, stream>>>(w, bs[0], ws);
  build_half_kernel<<<(80 * KCO_STRIDE + 255) / 256, 256, 0, stream>>>(
      w, ws, bs[0], bs[1], bs[2], bs[3], bs[4], bs[5], bs[6], bs[7], bs[8]);
  conv_mfma<<<dim3(8, 4, NBATCH), 256, 0, stream>>>(x, ws, out);
}

// Round 3
// 364.633 us; speedup vs baseline: 2.9686x; 1.2058x over previous
//
#include <hip/hip_runtime.h>
#include <hip/hip_fp16.h>
#include <math.h>

// Problem constants
#define NCH 72            // total channels (8*1 + 8*3 + 8*5)
#define SP  32768         // 32^3 spatial
#define NBATCH 8
#define NTOT (NBATCH*SP)  // per-channel element count = 262144

// ws layout (float offsets for the small stuff)
#define WS_SUMX   0       // 72
#define WS_SUMSQ  72      // 72
#define WS_SCALE  144     // 72 (per input channel inverse-std)
#define WS_BIAS   216     // 72
#define WS_K      288     // fp16 kernel matrix: 80co * 9tap * 224kk shorts = 322,560 B

// byte offsets / strides for the packed fp16 x tensor (fast path)
#define WS_XH_BYTES 323712          // 288*4 + 322560, 16B aligned
#define XH_ROW   2720               // 34 x-slots * 80 ci  (elements)
#define XH_PLANE 87040              // 32 * XH_ROW
#define XH_BATCH 2785280            // 32 * XH_PLANE
#define XH_NEED_BYTES (WS_XH_BYTES + (size_t)NBATCH * XH_BATCH * 2)  // 44,888,192

#define KCO_STRIDE 2016   // 9*224 elements per co row
#define KTAP_STRIDE 224
#define CP 88             // ci slots for the FALLBACK LDS path
#define XW 34
#define XROW (XW*CP)
#define XSLOT (6*XROW)

typedef __attribute__((ext_vector_type(8))) _Float16 half8;
typedef __attribute__((ext_vector_type(4))) float float4v;
typedef __attribute__((ext_vector_type(4))) int int4v;

__device__ __forceinline__ void chmap(int c, int& f, int& m, int& d, int& dim) {
  if (c < 8)       { f = 0; m = c;          d = 0;          dim = 1; }
  else if (c < 32) { f = 1; m = (c - 8)/3;  d = (c - 8)%3;  dim = 3; }
  else             { f = 2; m = (c - 32)/5; d = (c - 32)%5; dim = 5; }
}

// ---------------- fallback stats: per-channel sum(x), sum(x^2) ----------------
__global__ __launch_bounds__(256) void stats_kernel(const float* __restrict__ x,
                                                    float* __restrict__ ws) {
  const int c = blockIdx.x;
  const int b = blockIdx.y;
  const float4* p = (const float4*)(x + ((size_t)b * NCH + c) * SP);
  float sx = 0.f, sq = 0.f;
  for (int i = threadIdx.x; i < SP/4; i += 256) {
    float4 v = p[i];
    sx += v.x + v.y + v.z + v.w;
    sq += v.x*v.x + v.y*v.y + v.z*v.z + v.w*v.w;
  }
  #pragma unroll
  for (int o = 32; o > 0; o >>= 1) {
    sx += __shfl_down(sx, o, 64);
    sq += __shfl_down(sq, o, 64);
  }
  __shared__ float ssx[4], ssq[4];
  const int wid = threadIdx.x >> 6;
  if ((threadIdx.x & 63) == 0) { ssx[wid] = sx; ssq[wid] = sq; }
  __syncthreads();
  if (threadIdx.x == 0) {
    atomicAdd(&ws[WS_SUMX  + c], ssx[0]+ssx[1]+ssx[2]+ssx[3]);
    atomicAdd(&ws[WS_SUMSQ + c], ssq[0]+ssq[1]+ssq[2]+ssq[3]);
  }
}

// ---------------- fast path: transpose x -> fp16 [b][z][y][x][ci(80)] + fused stats ----
// grid (64, 8): blockIdx.x = z*2 + half;  each block = half a z-plane (512 pos, 2 chunks)
__global__ __launch_bounds__(256) void prepack_kernel(const float* __restrict__ x,
                                                      float* __restrict__ ws) {
  __shared__ __align__(16) short tile[256 * 88];   // [pos(256)][ci(88 pad)]
  __shared__ float segS[72][3], segQ[72][3];
  const int t    = threadIdx.x;
  const int z    = blockIdx.x >> 1;
  const int half = blockIdx.x & 1;
  const int b    = blockIdx.y;
  ushort* xh = (ushort*)((char*)ws + WS_XH_BYTES);
  const float* xb = x + (size_t)b * NCH * SP + z * 1024 + half * 512;

  const int ci_s = t % 72, seg = t / 72;   // stats mapping (t < 216)
  float accS = 0.f, accQ = 0.f;

  for (int c = 0; c < 2; ++c) {
    if (c) __syncthreads();                 // protect tile reuse
    // phase 1: coalesced fp32 load, fp16 convert, LDS transpose write
    #pragma unroll 4
    for (int ci = 0; ci < 72; ++ci) {
      const float v = xb[(size_t)ci * SP + c * 256 + t];
      tile[t * 88 + ci] = __half_as_short(__float2half(v));
    }
    __syncthreads();
    // phase 2a: coalesced global writeout (72 ci = 9 x b128 per pos)
    {
      const int pos = half * 512 + c * 256 + t;
      const int y = pos >> 5, xx = pos & 31;
      ushort* dst = xh + (size_t)b * XH_BATCH + (z * 32 + y) * XH_ROW + xx * 80;
      const int4v* src = (const int4v*)&tile[t * 88];
      #pragma unroll
      for (int k = 0; k < 9; ++k) ((int4v*)dst)[k] = src[k];
    }
    // phase 2b: stats from the tile (per-ci column sums)
    if (seg < 3) {
      const int p0 = seg * 86;
      const int pn = (seg == 2) ? 84 : 86;
      for (int i = 0; i < pn; ++i) {
        const float v = __half2float(__short_as_half(tile[(p0 + i) * 88 + ci_s]));
        accS += v; accQ += v * v;
      }
    }
  }
  if (seg < 3) { segS[ci_s][seg] = accS; segQ[ci_s][seg] = accQ; }
  __syncthreads();
  if (t < 144) {
    const int which = t / 72, ci = t % 72;
    const float v = which ? (segQ[ci][0] + segQ[ci][1] + segQ[ci][2])
                          : (segS[ci][0] + segS[ci][1] + segS[ci][2]);
    atomicAdd(&ws[(which ? WS_SUMSQ : WS_SUMX) + ci], v);
  }
}

// ---------------- finalize: scales, means -> bias ----------------
__global__ __launch_bounds__(128) void finalize_kernel(const float* __restrict__ weight,
                                                       const float* __restrict__ basis00,
                                                       float* __restrict__ ws) {
  __shared__ float s_mean[8], s_scale[8];
  const int c = threadIdx.x;
  const float invN = 1.0f / (float)NTOT;
  if (c < NCH) {
    float norm;
    if (c < 8) {
      float m = ws[WS_SUMX + c] * invN;
      norm = ws[WS_SUMSQ + c] * invN - m * m;
      s_mean[c] = m;
    } else if (c < 32) {
      int m0 = 8 + ((c - 8) / 3) * 3;
      norm = (ws[WS_SUMSQ+m0] + ws[WS_SUMSQ+m0+1] + ws[WS_SUMSQ+m0+2]) * invN;
    } else {
      int m0 = 32 + ((c - 32) / 5) * 5;
      norm = (ws[WS_SUMSQ+m0] + ws[WS_SUMSQ+m0+1] + ws[WS_SUMSQ+m0+2]
            + ws[WS_SUMSQ+m0+3] + ws[WS_SUMSQ+m0+4]) * invN;
    }
    float sc = 1.0f / sqrtf(norm + 1e-5f);
    ws[WS_SCALE + c] = sc;
    if (c < 8) s_scale[c] = sc;
  }
  __syncthreads();
  if (c < NCH) {
    float bia = 0.f;
    if (c < 8) {
      float id0 = 0.f, id1 = 0.f;
      #pragma unroll
      for (int t = 0; t < 27; ++t) { id0 += basis00[t]; id1 += basis00[27 + t]; }
      #pragma unroll
      for (int v = 0; v < 8; ++v) {
        float s  = s_scale[v];
        float w0 = weight[(c*8 + v)*2 + 0] * s;
        float w1 = weight[(c*8 + v)*2 + 1] * s;
        bia -= (w0 * id0 + w1 * id1) * s_mean[v];
      }
    }
    ws[WS_BIAS + c] = bia;
  }
}

// ---------------- build fp16 kernel matrix Kmat[co(80)][tap(9)][kk(224)] ----------------
__global__ __launch_bounds__(256) void build_half_kernel(const float* __restrict__ weight,
    float* __restrict__ ws,
    const float* __restrict__ b00, const float* __restrict__ b01, const float* __restrict__ b02,
    const float* __restrict__ b10, const float* __restrict__ b11, const float* __restrict__ b12,
    const float* __restrict__ b20, const float* __restrict__ b21, const float* __restrict__ b22) {
  const int tid = blockIdx.x * 256 + threadIdx.x;
  if (tid >= 80 * KCO_STRIDE) return;
  const int co  = tid / KCO_STRIDE;
  const int rem = tid - co * KCO_STRIDE;
  const int tap = rem / KTAP_STRIDE;
  const int kk  = rem - tap * KTAP_STRIDE;
  short val = 0;
  if (co < NCH && kk < 216) {
    const int dx = kk / 72, ci = kk - dx * 72;
    int fi, u, dd, di; chmap(co, fi, u, dd, di);
    int fj, v, ee, dj; chmap(ci, fj, v, ee, dj);
    const float* bs[9] = {b00, b01, b02, b10, b11, b12, b20, b21, b22};
    const float* basis = bs[fi * 3 + fj];
    const float sc = ws[WS_SCALE + ci];
    const float* wp = weight + (fi * 3 + fj) * 128 + (u * 8 + v) * 2;
    const float w0 = wp[0] * sc, w1 = wp[1] * sc;
    const int t = tap * 3 + dx;
    const float f = w0 * basis[(dd * dj + ee) * 27 + t]
                  + w1 * basis[((di + dd) * dj + ee) * 27 + t];
    val = __half_as_short(__float2half(f));
  }
  ((short*)(ws + WS_K))[tid] = val;
}

// ---------------- fast conv: no LDS, no barriers; A/B direct from global ----------------
// grid (15 z-pairs, 8 y-tiles, 8 b); wave w -> y = yt*4+w; wave m-tile = 2z x 32x.
__global__ __launch_bounds__(256, 3) void conv_direct(const float* __restrict__ ws,
                                                      float* __restrict__ out) {
  const int lane = threadIdx.x & 63;
  const int w    = threadIdx.x >> 6;
  const int lx   = lane & 15;
  const int q    = lane >> 4;
  const int y_s  = __builtin_amdgcn_readfirstlane(blockIdx.y * 4 + w);
  if (y_s >= 30) return;                       // whole-wave uniform exit, no barriers used
  const int zb = blockIdx.x * 2;
  const int b  = blockIdx.z;

  const char* xhb = (const char*)ws + WS_XH_BYTES + (size_t)b * (XH_BATCH * 2);
  const char* Kb  = (const char*)(ws + WS_K);
  const float* __restrict__ bias = ws + WS_BIAS;

  // byte offsets: A per kc, B per cj (lane-varying, loop-invariant)
  int aoffb[7], vboffb[5];
  #pragma unroll
  for (int kc = 0; kc < 7; ++kc) {
    const int kk0 = kc * 32 + q * 8;
    const int dx = (kk0 >= 144) ? 2 : ((kk0 >= 72) ? 1 : 0);
    aoffb[kc] = (lx * 80 + kk0 + 8 * dx) * 2;
  }
  #pragma unroll
  for (int cj = 0; cj < 5; ++cj) vboffb[cj] = (lx * KCO_STRIDE + q * 8 + cj * 16 * KCO_STRIDE) * 2;

  float4v acc[2][2][5];
  #pragma unroll
  for (int sz = 0; sz < 2; ++sz)
    #pragma unroll
    for (int s = 0; s < 2; ++s)
      #pragma unroll
      for (int cj = 0; cj < 5; ++cj)
        acc[sz][s][cj] = (float4v){0.f, 0.f, 0.f, 0.f};

  for (int dz = 0; dz < 3; ++dz) {
    for (int dy = 0; dy < 3; ++dy) {
      const char* r0 = xhb + (size_t)(((zb + dz) * 32) + (y_s + dy)) * (XH_ROW * 2);
      const char* r1 = r0 + (XH_PLANE * 2);
      const char* bk = Kb + (dz * 3 + dy) * (KTAP_STRIDE * 2);
      #pragma unroll
      for (int kc = 0; kc < 7; ++kc) {
        half8 bf[5];
        #pragma unroll
        for (int cj = 0; cj < 5; ++cj)
          bf[cj] = *(const half8*)(bk + vboffb[cj] + kc * 64);
        const half8 a00 = *(const half8*)(r0 + aoffb[kc]);
        const half8 a01 = *(const half8*)(r0 + aoffb[kc] + 2560);   // +16 x-slots
        const half8 a10 = *(const half8*)(r1 + aoffb[kc]);
        const half8 a11 = *(const half8*)(r1 + aoffb[kc] + 2560);
        #pragma unroll
        for (int cj = 0; cj < 5; ++cj) {
          acc[0][0][cj] = __builtin_amdgcn_mfma_f32_16x16x32_f16(a00, bf[cj], acc[0][0][cj], 0, 0, 0);
          acc[0][1][cj] = __builtin_amdgcn_mfma_f32_16x16x32_f16(a01, bf[cj], acc[0][1][cj], 0, 0, 0);
          acc[1][0][cj] = __builtin_amdgcn_mfma_f32_16x16x32_f16(a10, bf[cj], acc[1][0][cj], 0, 0, 0);
          acc[1][1][cj] = __builtin_amdgcn_mfma_f32_16x16x32_f16(a11, bf[cj], acc[1][1][cj], 0, 0, 0);
        }
      }
    }
  }

  // epilogue: D layout col(co)=lane&15, row(m=x)=q*4+reg
  #pragma unroll
  for (int cj = 0; cj < 5; ++cj) {
    const int co = cj * 16 + lx;
    if (co < NCH) {
      const float bv = bias[co];
      #pragma unroll
      for (int sz = 0; sz < 2; ++sz) {
        float* ob = out + ((size_t)(b * NCH + co) * 30 + (zb + sz)) * 900 + y_s * 30;
        #pragma unroll
        for (int s = 0; s < 2; ++s) {
          const int x0 = s * 16 + q * 4;
          const float4v v = acc[sz][s][cj];
          float2 p0; p0.x = v[0] + bv; p0.y = v[1] + bv;
          *(float2*)(ob + x0) = p0;
          if (x0 + 2 < 30) {
            float2 p1; p1.x = v[2] + bv; p1.y = v[3] + bv;
            *(float2*)(ob + x0 + 2) = p1;
          }
        }
      }
    }
  }
}

// ---------------- fallback conv (round-2, known-good) ----------------
__device__ __forceinline__ void stage_plane(const float* __restrict__ xb, int zp, int yr0,
                                            short* sX) {
  short* dst = sX + (zp & 3) * XSLOT;
  for (int i = threadIdx.x; i < NCH * 204; i += 256) {
    const int ci  = i / 204;
    const int rem = i - ci * 204;
    const int yp  = rem / XW;
    const int xx  = rem - yp * XW;
    int ys = yr0 + yp; if (ys > 31) ys = 31;
    int xs = xx;       if (xs > 31) xs = 31;
    const float v = xb[(size_t)ci * SP + zp * 1024 + ys * 32 + xs];
    dst[rem * CP + ci] = __half_as_short(__float2half(v));
  }
}

__global__ __launch_bounds__(256) void conv_mfma(const float* __restrict__ x,
                                                 const float* __restrict__ ws,
                                                 float* __restrict__ out) {
  __shared__ __align__(16) short sX[4 * XSLOT];
  const int tid  = threadIdx.x;
  const int lane = tid & 63;
  const int w    = tid >> 6;
  const int lx   = lane & 15;
  const int q    = lane >> 4;
  const int yt = blockIdx.x, zc = blockIdx.y, b = blockIdx.z;
  const int y0 = yt * 4, y = y0 + w;
  const int z0 = zc * 8, z1 = (z0 + 8 < 30) ? z0 + 8 : 30;
  const float* __restrict__ xb   = x + (size_t)b * NCH * SP;
  const short* __restrict__ Kmat = (const short*)(ws + WS_K);
  const float* __restrict__ bias = ws + WS_BIAS;

  int dxk[7], cik[7];
  #pragma unroll
  for (int kc = 0; kc < 7; ++kc) {
    const int kk0 = kc * 32 + q * 8;
    const int dx = (kk0 >= 144) ? 2 : ((kk0 >= 72) ? 1 : 0);
    dxk[kc] = dx; cik[kc] = kk0 - dx * 72;
  }
  const short* bbase = Kmat + lx * KCO_STRIDE + q * 8;

  for (int i = tid; i < 4 * 204 * 16; i += 256) {
    const int sl = i / (204 * 16);
    const int r2 = i - sl * (204 * 16);
    sX[sl * XSLOT + (r2 >> 4) * CP + 72 + (r2 & 15)] = 0;
  }
  stage_plane(xb, z0,     y0, sX);
  stage_plane(xb, z0 + 1, y0, sX);
  stage_plane(xb, z0 + 2, y0, sX);
  stage_plane(xb, z0 + 3, y0, sX);

  for (int zb = z0; zb < z1; zb += 2) {
    if (zb > z0) {
      __syncthreads();
      stage_plane(xb, zb + 2, y0, sX);
      stage_plane(xb, zb + 3, y0, sX);
    }
    __syncthreads();

    float4v acc[2][2][5];
    #pragma unroll
    for (int sz = 0; sz < 2; ++sz)
      #pragma unroll
      for (int s = 0; s < 2; ++s)
        #pragma unroll
        for (int cj = 0; cj < 5; ++cj)
          acc[sz][s][cj] = (float4v){0.f, 0.f, 0.f, 0.f};

    for (int tap = 0; tap < 9; ++tap) {
      const int dz = tap / 3, dy = tap - dz * 3;
      const short* ab0 = sX + ((zb + dz) & 3)     * XSLOT + (w + dy) * XROW;
      const short* ab1 = sX + ((zb + 1 + dz) & 3) * XSLOT + (w + dy) * XROW;
      #pragma unroll
      for (int kc = 0; kc < 7; ++kc) {
        const short* bp = bbase + tap * KTAP_STRIDE + kc * 32;
        half8 bf[5];
        #pragma unroll
        for (int cj = 0; cj < 5; ++cj)
          bf[cj] = *(const half8*)(bp + cj * 16 * KCO_STRIDE);
        const int xoff = (lx + dxk[kc]) * CP + cik[kc];
        const half8 a00 = *(const half8*)(ab0 + xoff);
        const half8 a01 = *(const half8*)(ab0 + 16 * CP + xoff);
        const half8 a10 = *(const half8*)(ab1 + xoff);
        const half8 a11 = *(const half8*)(ab1 + 16 * CP + xoff);
        #pragma unroll
        for (int cj = 0; cj < 5; ++cj) {
          acc[0][0][cj] = __builtin_amdgcn_mfma_f32_16x16x32_f16(a00, bf[cj], acc[0][0][cj], 0, 0, 0);
          acc[0][1][cj] = __builtin_amdgcn_mfma_f32_16x16x32_f16(a01, bf[cj], acc[0][1][cj], 0, 0, 0);
          acc[1][0][cj] = __builtin_amdgcn_mfma_f32_16x16x32_f16(a10, bf[cj], acc[1][0][cj], 0, 0, 0);
          acc[1][1][cj] = __builtin_amdgcn_mfma_f32_16x16x32_f16(a11, bf[cj], acc[1][1][cj], 0, 0, 0);
        }
      }
    }

    if (y < 30) {
      #pragma unroll
      for (int cj = 0; cj < 5; ++cj) {
        const int co = cj * 16 + lx;
        if (co < NCH) {
          const float bv = bias[co];
          #pragma unroll
          for (int sz = 0; sz < 2; ++sz) {
            float* ob = out + ((size_t)(b * NCH + co) * 30 + (zb + sz)) * 900 + y * 30;
            #pragma unroll
            for (int s = 0; s < 2; ++s) {
              const int x0 = s * 16 + q * 4;
              const float4v v = acc[sz][s][cj];
              float2 p0; p0.x = v[0] + bv; p0.y = v[1] + bv;
              *(float2*)(ob + x0) = p0;
              if (x0 + 2 < 30) {
                float2 p1; p1.x = v[2] + bv; p1.y = v[3] + bv;
                *(float2*)(ob + x0 + 2) = p1;
              }
            }
          }
        }
      }
    }
  }
}

extern "C" void kernel_launch(void* const* d_in, const int* in_sizes, int n_in,
                              void* d_out, int out_size, void* d_ws, size_t ws_size,
                              hipStream_t stream) {
  const float* x = (const float*)d_in[0];
  const float* w = (const float*)d_in[1];
  const float* bs[9];
  for (int i = 0; i < 9; ++i) bs[i] = (const float*)d_in[2 + i];
  float* ws  = (float*)d_ws;
  float* out = (float*)d_out;

  hipMemsetAsync(d_ws, 0, 144 * sizeof(float), stream);   // stats accumulators

  const bool fast = ws_size >= XH_NEED_BYTES;   // constant across calls -> capture-safe
  if (fast) {
    prepack_kernel<<<dim3(64, NBATCH), 256, 0, stream>>>(x, ws);
    finalize_kernel<<<1, 128, 0, stream>>>(w, bs[0], ws);
    build_half_kernel<<<(80 * KCO_STRIDE + 255) / 256, 256, 0, stream>>>(
        w, ws, bs[0], bs[1], bs[2], bs[3], bs[4], bs[5], bs[6], bs[7], bs[8]);
    conv_direct<<<dim3(15, 8, NBATCH), 256, 0, stream>>>(ws, out);
  } else {
    stats_kernel<<<dim3(NCH, NBATCH), 256, 0, stream>>>(x, ws);
    finalize_kernel<<<1, 128, 0, stream>>>(w, bs[0], ws);
    build_half_kernel<<<(80 * KCO_STRIDE + 255) / 256, 256, 0, stream>>>(
        w, ws, bs[0], bs[1], bs[2], bs[3], bs[4], bs[5], bs[6], bs[7], bs[8]);
    conv_mfma<<<dim3(8, 4, NBATCH), 256, 0, stream>>>(x, ws, out);
  }
}

// Round 5
// 342.761 us; speedup vs baseline: 3.1581x; 1.0638x over previous
//
#include <hip/hip_runtime.h>
#include <hip/hip_fp16.h>
#include <math.h>

// Problem constants
#define NCH 72            // total channels (8*1 + 8*3 + 8*5)
#define SP  32768         // 32^3 spatial
#define NBATCH 8
#define NTOT (NBATCH*SP)  // per-channel element count = 262144

// ws layout (float offsets for the small stuff)
#define WS_SUMX   0       // 72
#define WS_SUMSQ  72      // 72
#define WS_SCALE  144     // 72 (per input channel inverse-std)
#define WS_BIAS   216     // 72
#define WS_K      288     // fp16 kernel matrix, fragment-blocked: 315 blocks * 1024 B

// byte offsets / strides for the packed fp16 x tensor
#define WS_XH_BYTES 323712          // 288*4 + 322560, 16B aligned
#define XH_ROW   2720               // 34 x-slots * 80 ci  (elements)
#define XH_PLANE 87040              // 32 * XH_ROW
#define XH_BATCH 2785280            // 32 * XH_PLANE

typedef __attribute__((ext_vector_type(8))) _Float16 half8;
typedef __attribute__((ext_vector_type(4))) float float4v;
typedef __attribute__((ext_vector_type(4))) int int4v;

__device__ __forceinline__ void chmap(int c, int& f, int& m, int& d, int& dim) {
  if (c < 8)       { f = 0; m = c;          d = 0;          dim = 1; }
  else if (c < 32) { f = 1; m = (c - 8)/3;  d = (c - 8)%3;  dim = 3; }
  else             { f = 2; m = (c - 32)/5; d = (c - 32)%5; dim = 5; }
}

// ---------------- prepack: x -> fp16 [b][z][y][x(34)][ci(80)] + fused BN stats ----------
// grid (64, 8): blockIdx.x = z*2 + half; block = half a z-plane (2 chunks of 256 pos)
__global__ __launch_bounds__(256) void prepack_kernel(const float* __restrict__ x,
                                                      float* __restrict__ ws) {
  __shared__ __align__(16) short tile[256 * 88];   // [pos(256)][ci(88 pad)] = 45 KB
  __shared__ float segS[72][3], segQ[72][3];
  const int t    = threadIdx.x;
  const int z    = blockIdx.x >> 1;
  const int half = blockIdx.x & 1;
  const int b    = blockIdx.y;
  ushort* xh = (ushort*)((char*)ws + WS_XH_BYTES);
  const float* xb = x + (size_t)b * NCH * SP + z * 1024 + half * 512;

  const int ci_s = t % 72, seg = t / 72;   // stats mapping (t < 216)
  float accS = 0.f, accQ = 0.f;

  // zero the ci pad (72..79) once: phase 2a copies it into the packed tensor, and
  // the conv multiplies it by B=0 -- stale LDS Inf/NaN would make 0*Inf = NaN.
  *(int4v*)&tile[t * 88 + 72] = (int4v){0, 0, 0, 0};

  for (int c = 0; c < 2; ++c) {
    if (c) __syncthreads();                 // protect tile reuse
    // phase 1: coalesced fp32 loads (fully unrolled -> deep MLP), short4 LDS writes
    #pragma unroll
    for (int cig = 0; cig < 18; ++cig) {
      float v0 = xb[(size_t)(cig*4 + 0) * SP + c * 256 + t];
      float v1 = xb[(size_t)(cig*4 + 1) * SP + c * 256 + t];
      float v2 = xb[(size_t)(cig*4 + 2) * SP + c * 256 + t];
      float v3 = xb[(size_t)(cig*4 + 3) * SP + c * 256 + t];
      short s4[4] = { (short)__half_as_short(__float2half(v0)),
                      (short)__half_as_short(__float2half(v1)),
                      (short)__half_as_short(__float2half(v2)),
                      (short)__half_as_short(__float2half(v3)) };
      *(int2*)&tile[t * 88 + cig * 4] = *(const int2*)s4;   // 8B aligned
    }
    __syncthreads();
    // phase 2a: coalesced writeout — 2560 16B segments (10 per pos), consecutive lanes
    {
      ushort* gb = xh + (size_t)b * XH_BATCH + (size_t)(z * 32 + (half * 2 + c) * 8) * XH_ROW;
      #pragma unroll
      for (int j = 0; j < 10; ++j) {
        const int s   = t + j * 256;        // 0..2559
        const int pos = s / 10, part = s - pos * 10;
        const int4v v = *(const int4v*)&tile[pos * 88 + part * 8];
        const int row = pos >> 5, xx = pos & 31;
        *(int4v*)(gb + (size_t)row * XH_ROW + xx * 80 + part * 8) = v;
      }
    }
    // phase 2b: stats from the tile (per-ci column sums)
    if (seg < 3) {
      const int p0 = seg * 86;
      const int pn = (seg == 2) ? 84 : 86;
      for (int i = 0; i < pn; ++i) {
        const float v = __half2float(__short_as_half(tile[(p0 + i) * 88 + ci_s]));
        accS += v; accQ += v * v;
      }
    }
  }
  if (seg < 3) { segS[ci_s][seg] = accS; segQ[ci_s][seg] = accQ; }
  __syncthreads();
  if (t < 144) {
    const int which = t / 72, ci = t % 72;
    const float v = which ? (segQ[ci][0] + segQ[ci][1] + segQ[ci][2])
                          : (segS[ci][0] + segS[ci][1] + segS[ci][2]);
    atomicAdd(&ws[(which ? WS_SUMSQ : WS_SUMX) + ci], v);
  }
}

// ---------------- finalize: scales, means -> bias ----------------
__global__ __launch_bounds__(128) void finalize_kernel(const float* __restrict__ weight,
                                                       const float* __restrict__ basis00,
                                                       float* __restrict__ ws) {
  __shared__ float s_mean[8], s_scale[8];
  const int c = threadIdx.x;
  const float invN = 1.0f / (float)NTOT;
  if (c < NCH) {
    float norm;
    if (c < 8) {
      float m = ws[WS_SUMX + c] * invN;
      norm = ws[WS_SUMSQ + c] * invN - m * m;
      s_mean[c] = m;
    } else if (c < 32) {
      int m0 = 8 + ((c - 8) / 3) * 3;
      norm = (ws[WS_SUMSQ+m0] + ws[WS_SUMSQ+m0+1] + ws[WS_SUMSQ+m0+2]) * invN;
    } else {
      int m0 = 32 + ((c - 32) / 5) * 5;
      norm = (ws[WS_SUMSQ+m0] + ws[WS_SUMSQ+m0+1] + ws[WS_SUMSQ+m0+2]
            + ws[WS_SUMSQ+m0+3] + ws[WS_SUMSQ+m0+4]) * invN;
    }
    float sc = 1.0f / sqrtf(norm + 1e-5f);
    ws[WS_SCALE + c] = sc;
    if (c < 8) s_scale[c] = sc;
  }
  __syncthreads();
  if (c < NCH) {
    float bia = 0.f;
    if (c < 8) {
      float id0 = 0.f, id1 = 0.f;
      #pragma unroll
      for (int t = 0; t < 27; ++t) { id0 += basis00[t]; id1 += basis00[27 + t]; }
      #pragma unroll
      for (int v = 0; v < 8; ++v) {
        float s  = s_scale[v];
        float w0 = weight[(c*8 + v)*2 + 0] * s;
        float w1 = weight[(c*8 + v)*2 + 1] * s;
        bia -= (w0 * id0 + w1 * id1) * s_mean[v];
      }
    }
    ws[WS_BIAS + c] = bia;
  }
}

// ---------------- build fp16 kernel matrix, fragment-blocked layout ----------------
// 315 blocks of 1024 B: block = tap*35 + kc*5 + cj; element e: lane l = e/8, j = e%8;
// co = cj*16 + (l&15);  kk = kc*32 + (l>>4)*8 + j  (zero for co>=72 or kk>=216)
__global__ __launch_bounds__(256) void build_half_kernel(const float* __restrict__ weight,
    float* __restrict__ ws,
    const float* __restrict__ b00, const float* __restrict__ b01, const float* __restrict__ b02,
    const float* __restrict__ b10, const float* __restrict__ b11, const float* __restrict__ b12,
    const float* __restrict__ b20, const float* __restrict__ b21, const float* __restrict__ b22) {
  const int tid = blockIdx.x * 256 + threadIdx.x;
  if (tid >= 315 * 512) return;
  const int blk = tid >> 9;
  const int e   = tid & 511;
  const int tap = blk / 35;
  const int r   = blk - tap * 35;
  const int kc  = r / 5, cj = r - (r / 5) * 5;
  const int l   = e >> 3, j = e & 7;
  const int co  = cj * 16 + (l & 15);
  const int kk  = kc * 32 + ((l >> 4) << 3) + j;
  short val = 0;
  if (co < NCH && kk < 216) {
    const int dx = kk / 72, ci = kk - dx * 72;
    int fi, u, dd, di; chmap(co, fi, u, dd, di);
    int fj, v, ee, dj; chmap(ci, fj, v, ee, dj);
    const float* bs[9] = {b00, b01, b02, b10, b11, b12, b20, b21, b22};
    const float* basis = bs[fi * 3 + fj];
    const float sc = ws[WS_SCALE + ci];
    const float* wp = weight + (fi * 3 + fj) * 128 + (u * 8 + v) * 2;
    const float w0 = wp[0] * sc, w1 = wp[1] * sc;
    const int t = tap * 3 + dx;
    const float f = w0 * basis[(dd * dj + ee) * 27 + t]
                  + w1 * basis[((di + dd) * dj + ee) * 27 + t];
    val = __half_as_short(__float2half(f));
  }
  ((short*)(ws + WS_K))[tid] = val;
}

// ---------------- conv: 1-wave blocks, XCD-swizzled, A/B direct from cache ----------------
// 3600 blocks of 64 threads. XCD r = blk%8 = batch; within XCD: zp rolls 0..14 (L2 window),
// y = fastest. Wave m-tile: 2z x 32x at one y; n = 80 co; k = 2016.
__global__ __launch_bounds__(64, 3) void conv_direct(const float* __restrict__ ws,
                                                     float* __restrict__ out) {
  const int lane = threadIdx.x;
  const int lx   = lane & 15;
  const int q    = lane >> 4;
  const int i  = blockIdx.x;
  const int b  = i & 7;              // XCD-pinned batch
  const int qq = i >> 3;             // 0..449
  const int y  = qq % 30;
  const int zp = qq / 30;            // 0..14
  const int zb = zp * 2;

  const char* xhb = (const char*)ws + WS_XH_BYTES + (size_t)b * (XH_BATCH * 2);
  const char* Kb  = (const char*)(ws + WS_K);
  const float* __restrict__ bias = ws + WS_BIAS;

  int aoffb[7];
  #pragma unroll
  for (int kc = 0; kc < 7; ++kc) {
    const int kk0 = kc * 32 + q * 8;
    const int dx = (kk0 >= 144) ? 2 : ((kk0 >= 72) ? 1 : 0);
    aoffb[kc] = (lx * 80 + kk0 + 8 * dx) * 2;
  }
  const int lb16 = lane * 16;        // B-fragment: contiguous 1KB block + lane*16

  float4v acc[2][2][5];
  #pragma unroll
  for (int sz = 0; sz < 2; ++sz)
    #pragma unroll
    for (int s = 0; s < 2; ++s)
      #pragma unroll
      for (int cj = 0; cj < 5; ++cj)
        acc[sz][s][cj] = (float4v){0.f, 0.f, 0.f, 0.f};

  for (int dz = 0; dz < 3; ++dz) {
    for (int dy = 0; dy < 3; ++dy) {
      const char* r0 = xhb + (size_t)(((zb + dz) * 32) + (y + dy)) * (XH_ROW * 2);
      const char* r1 = r0 + (XH_PLANE * 2);
      const char* bk = Kb + (size_t)(dz * 3 + dy) * 35 * 1024 + lb16;
      #pragma unroll
      for (int kc = 0; kc < 7; ++kc) {
        half8 bf[5];
        #pragma unroll
        for (int cj = 0; cj < 5; ++cj)
          bf[cj] = *(const half8*)(bk + (kc * 5 + cj) * 1024);
        const half8 a00 = *(const half8*)(r0 + aoffb[kc]);
        const half8 a01 = *(const half8*)(r0 + aoffb[kc] + 2560);   // +16 x-slots
        const half8 a10 = *(const half8*)(r1 + aoffb[kc]);
        const half8 a11 = *(const half8*)(r1 + aoffb[kc] + 2560);
        #pragma unroll
        for (int cj = 0; cj < 5; ++cj) {
          acc[0][0][cj] = __builtin_amdgcn_mfma_f32_16x16x32_f16(a00, bf[cj], acc[0][0][cj], 0, 0, 0);
          acc[0][1][cj] = __builtin_amdgcn_mfma_f32_16x16x32_f16(a01, bf[cj], acc[0][1][cj], 0, 0, 0);
          acc[1][0][cj] = __builtin_amdgcn_mfma_f32_16x16x32_f16(a10, bf[cj], acc[1][0][cj], 0, 0, 0);
          acc[1][1][cj] = __builtin_amdgcn_mfma_f32_16x16x32_f16(a11, bf[cj], acc[1][1][cj], 0, 0, 0);
        }
      }
    }
  }

  // epilogue: D layout col(co)=lane&15, row(m=x)=q*4+reg
  #pragma unroll
  for (int cj = 0; cj < 5; ++cj) {
    const int co = cj * 16 + lx;
    if (co < NCH) {
      const float bv = bias[co];
      #pragma unroll
      for (int sz = 0; sz < 2; ++sz) {
        float* ob = out + ((size_t)(b * NCH + co) * 30 + (zb + sz)) * 900 + y * 30;
        #pragma unroll
        for (int s = 0; s < 2; ++s) {
          const int x0 = s * 16 + q * 4;
          const float4v v = acc[sz][s][cj];
          float2 p0; p0.x = v[0] + bv; p0.y = v[1] + bv;
          *(float2*)(ob + x0) = p0;
          if (x0 + 2 < 30) {
            float2 p1; p1.x = v[2] + bv; p1.y = v[3] + bv;
            *(float2*)(ob + x0 + 2) = p1;
          }
        }
      }
    }
  }
}

extern "C" void kernel_launch(void* const* d_in, const int* in_sizes, int n_in,
                              void* d_out, int out_size, void* d_ws, size_t ws_size,
                              hipStream_t stream) {
  const float* x = (const float*)d_in[0];
  const float* w = (const float*)d_in[1];
  const float* bs[9];
  for (int i = 0; i < 9; ++i) bs[i] = (const float*)d_in[2 + i];
  float* ws  = (float*)d_ws;
  float* out = (float*)d_out;

  hipMemsetAsync(d_ws, 0, 144 * sizeof(float), stream);   // stats accumulators

  prepack_kernel<<<dim3(64, NBATCH), 256, 0, stream>>>(x, ws);
  finalize_kernel<<<1, 128, 0, stream>>>(w, bs[0], ws);
  build_half_kernel<<<(315 * 512 + 255) / 256, 256, 0, stream>>>(
      w, ws, bs[0], bs[1], bs[2], bs[3], bs[4], bs[5], bs[6], bs[7], bs[8]);
  conv_direct<<<dim3(3600), 64, 0, stream>>>(ws, out);
}